// Round 1
// 300.014 us; speedup vs baseline: 1.1363x; 1.1363x over previous
//
#include <hip/hip_runtime.h>
#include <hip/hip_bf16.h>
#include <stdint.h>

// Problem: out[b,i] = sum_j a_ext[b,j] * W[hash_idx[i,j]]
//   B=4096, FAN_IN=4096 (+1 bias col), FAN_OUT=4096, K-table=65536
// Strategy: materialize bf16 A_ext [B][KP] and Wv [FAN_OUT][KP] (K padded
// 4097->4160), then bf16 MFMA GEMM-BT into fp32 C.
// R2: build_wv = LDS-resident two-phase gather (64KB half-table in LDS).
// R5: WIN: launch_bounds + hoisted ptrs: gemm 216->182us.
// R7: single-barrier LDS double-buffer 128x128 gemm: 180us, ~795 TF,
//     MfmaUtil 34% — the m97-structure ceiling. Conflicts 1.7e7 (64B rows).
// R8 (this): 256x256 8-phase template (m201-class): BK=64, 8 waves (2Mx4N),
//     128KB LDS dbuf, per-phase {ds_read || stage-1-half-tile -> barrier ->
//     lgkmcnt(0) -> setprio(1) -> 16 MFMA -> barrier}, counted vmcnt(4) once
//     per K-tile (never 0 in-loop), XOR swizzle slot^=(row&7) applied as
//     pre-swizzled GLOBAL stage source + swizzled ds_read (both-sides rule).
//     Stage schedule legality (tile t, buf p=t&1):
//       ph0: stage A1(t+1)->buf[p^1]  (whole buf[p^1] free since tile t-1 end)
//       ph1: stage B1(t+1)->buf[p^1]  (same)
//       ph2: stage B0(t+2)->buf[p]    (B(t) reads done: ph0/ph1 lgkm + ph1-end bar)
//       ph3: stage A0(t+2)->buf[p]    (A(t) reads done: ph0/ph2 lgkm + ph2-end bar)
//     Boundary: vmcnt(4) leaves exactly {B0,A0}(t+2) in flight. Always-issue
//     with clamped tile idx => stale-but-harmless writes into freed regions,
//     no epilogue special case. Final vmcnt(0) before C-write (LDS dealloc).

#define B_DIM   4096
#define FAN_IN  4096
#define FAN_OUT 4096
#define KD      (FAN_IN + 1)   // 4097
#define KP      4160           // padded: 65 * 64
#define NKT     65             // K-tiles of BK=64

#define BM 256
#define BN 256
#define BK 64

typedef __attribute__((ext_vector_type(8))) short  short8;   // 8 bf16 = 4 VGPRs
typedef __attribute__((ext_vector_type(4))) float  floatx4;  // MFMA acc

__device__ __forceinline__ unsigned short f2bf(float f) {
  union { float f; unsigned u; } v; v.f = f;
  unsigned u = v.u;
  u += 0x7fffu + ((u >> 16) & 1u);   // round-to-nearest-even
  return (unsigned short)(u >> 16);
}

__device__ __forceinline__ void async16(const void* g, void* l) {
  // direct global->LDS DMA, 16B/lane; LDS dest = wave-uniform base + lane*16
  __builtin_amdgcn_global_load_lds(
      (const __attribute__((address_space(1))) void*)g,
      (__attribute__((address_space(3))) void*)l, 16, 0, 0);
}

// ---- Kernel 1: A_ext[b][j] = bf16(a[b][j]); col 4096 = 1.0; cols 4097..KP-1 = 0
__global__ __launch_bounds__(256) void build_aext(
    const float* __restrict__ a, unsigned short* __restrict__ Ae) {
  const int row = blockIdx.x;
  const float* ar = a + (size_t)row * FAN_IN;
  unsigned short* er = Ae + (size_t)row * KP;
  for (int j4 = threadIdx.x; j4 < KP / 4; j4 += 256) {
    const int j = j4 * 4;
    float x0, x1, x2, x3;
    if (j + 3 < FAN_IN) {
      const float4 v = *(const float4*)(ar + j);   // 16B-aligned (row stride 16KB)
      x0 = v.x; x1 = v.y; x2 = v.z; x3 = v.w;
    } else {
      x0 = (j + 0 < FAN_IN) ? ar[j + 0] : ((j + 0 == FAN_IN) ? 1.0f : 0.0f);
      x1 = (j + 1 < FAN_IN) ? ar[j + 1] : ((j + 1 == FAN_IN) ? 1.0f : 0.0f);
      x2 = (j + 2 < FAN_IN) ? ar[j + 2] : ((j + 2 == FAN_IN) ? 1.0f : 0.0f);
      x3 = (j + 3 < FAN_IN) ? ar[j + 3] : ((j + 3 == FAN_IN) ? 1.0f : 0.0f);
    }
    ushort4 o;
    o.x = f2bf(x0); o.y = f2bf(x1); o.z = f2bf(x2); o.w = f2bf(x3);
    *(ushort4*)(er + j) = o;   // 8B store, aligned
  }
}

// ---- Kernel 2 (R2 version, measured-best): Wv[i][j] = bf16(W[hash_idx[i][j]]).
__global__ __launch_bounds__(512) void build_wv(
    const int* __restrict__ hidx, const float* __restrict__ W,
    unsigned short* __restrict__ Wv) {
  __shared__ unsigned short wl[32768];   // 64 KB: half of W as bf16
  const int t  = threadIdx.x;
  const int r0 = blockIdx.x * 4;

  int          idx[4][9];
  unsigned short res[4][9];
#pragma unroll
  for (int row = 0; row < 4; row++) {
    const int* hr = hidx + (size_t)(r0 + row) * KD;
#pragma unroll
    for (int i = 0; i < 9; i++) {
      const int j = i * 512 + t;
      idx[row][i] = (j < KD) ? hr[j] : 0;
      res[row][i] = 0;
    }
  }

  for (int h = 0; h < 2; h++) {
    __syncthreads();   // protect phase-0 reads before phase-1 refill
    const float4* Wb = (const float4*)(W + h * 32768);
#pragma unroll
    for (int i = 0; i < 16; i++) {
      const int f4 = i * 512 + t;
      const float4 v = Wb[f4];
      ushort4 o;
      o.x = f2bf(v.x); o.y = f2bf(v.y); o.z = f2bf(v.z); o.w = f2bf(v.w);
      *(ushort4*)&wl[f4 * 4] = o;
    }
    __syncthreads();
    const int lo = h << 15;
#pragma unroll
    for (int row = 0; row < 4; row++)
#pragma unroll
      for (int i = 0; i < 9; i++) {
        const int v = idx[row][i];
        if ((v & 32768) == lo)
          res[row][i] = wl[v & 32767];
      }
  }

#pragma unroll
  for (int row = 0; row < 4; row++) {
    unsigned short* wr = Wv + (size_t)(r0 + row) * KP;
#pragma unroll
    for (int i = 0; i < 9; i++) {
      const int j = i * 512 + t;
      if (j < KD) wr[j] = res[row][i];
    }
    if (t < KP - KD) wr[KD + t] = 0;
  }
}

// ---- Kernel 3 (R8): 256x256 8-phase GEMM-BT, bf16 in fp32 out.
// LDS layout (bytes, 128KB dynamic): A: buf*32768 + half*16384 + row*128 + slot*16
//   with physical slot = logical_slot ^ (row&7)  (slot = 16B chunk, 8 per row)
// B region at +65536, same layout.
// Stage half-tile (128 rows x 64 k): 2 calls/wave (c=0,1), wave w writes rows
//   c*64 + w*8 + (lane>>3), phys slot lane&7 carrying global slot (lane&7)^(lane>>3).

#define STAGE_A(buf, h, ts)                                                        \
  do {                                                                             \
    async16(pa + ((h) * 128 + 0)  * KP + (ts) * 64,                                \
            smb + ((buf) << 15) + ((h) << 14) + dA);                               \
    async16(pa + ((h) * 128 + 64) * KP + (ts) * 64,                                \
            smb + ((buf) << 15) + ((h) << 14) + 8192 + dA);                        \
  } while (0)

#define STAGE_B(buf, h, ts)                                                        \
  do {                                                                             \
    async16(pb + ((h) * 128 + 0)  * KP + (ts) * 64,                                \
            smb + 65536 + ((buf) << 15) + ((h) << 14) + dA);                       \
    async16(pb + ((h) * 128 + 64) * KP + (ts) * 64,                                \
            smb + 65536 + ((buf) << 15) + ((h) << 14) + 8192 + dA);                \
  } while (0)

#define PHASE_MID()                                                                \
  do {                                                                             \
    asm volatile("" ::: "memory");                                                 \
    __builtin_amdgcn_s_barrier();                                                  \
    asm volatile("s_waitcnt lgkmcnt(0)" ::: "memory");                             \
    __builtin_amdgcn_sched_barrier(0);                                             \
    __builtin_amdgcn_s_setprio(1);                                                 \
  } while (0)

#define PHASE_END()                                                                \
  do {                                                                             \
    __builtin_amdgcn_s_setprio(0);                                                 \
    asm volatile("" ::: "memory");                                                 \
    __builtin_amdgcn_s_barrier();                                                  \
    asm volatile("" ::: "memory");                                                 \
  } while (0)

#define PHASE_END_TILE()                                                           \
  do {                                                                             \
    __builtin_amdgcn_s_setprio(0);                                                 \
    asm volatile("s_waitcnt vmcnt(4)" ::: "memory");                               \
    __builtin_amdgcn_s_barrier();                                                  \
    asm volatile("" ::: "memory");                                                 \
  } while (0)

#define MFMA2(ACC, AF, BF)                                                         \
  do {                                                                             \
    ACC = __builtin_amdgcn_mfma_f32_16x16x32_bf16((AF)[0], (BF)[0], ACC, 0, 0, 0); \
    ACC = __builtin_amdgcn_mfma_f32_16x16x32_bf16((AF)[1], (BF)[1], ACC, 0, 0, 0); \
  } while (0)

__global__ __launch_bounds__(512, 2) void gemm_bt8(
    const unsigned short* __restrict__ A, const unsigned short* __restrict__ Bm,
    float* __restrict__ C, int M, int N) {
  extern __shared__ char smb[];   // 128 KB
  const int tid = threadIdx.x;
  const int l   = tid & 63;
  const int w   = tid >> 6;       // 8 waves
  const int wm  = w >> 2;         // 0..1  (M half: rows wm*128..+127)
  const int wn  = w & 3;          // 0..3  (N 64-col strip)
  const int bm  = blockIdx.y * BM;
  const int bn  = blockIdx.x * BN;
  const int q   = l >> 4;         // MFMA k-quad
  const int r   = l & 15;         // MFMA m/n-in-16

  // ---- staging source pointers (pre-swizzled global column) ----
  const int lrow = l >> 3;                       // 0..7 (row-in-8)
  const int lcol = ((l & 7) ^ lrow) * 8;         // swizzled 16B chunk (elements)
  const unsigned short* pa = A  + (size_t)(bm + w * 8 + lrow) * KP + lcol;
  const unsigned short* pb = Bm + (size_t)(bn + w * 8 + lrow) * KP + lcol;
  const int dA = w * 1024;                       // wave's byte base in 8KB slab

  // ---- swizzled ds_read byte offset (within a 16KB half region) ----
  // logical: row = mi*16 + r, slot = ks*4 + q; physical slot ^= (r&7)
  const int abase = r * 128 + ((q ^ (r & 7)) << 4);   // ks=0; ks=1 is ^64

  floatx4 acc[8][4] = {};

  // ---- prologue: tile0 -> buf0 (all 4 halves), then B0(1), A0(1) -> buf1 ----
  STAGE_A(0, 0, 0); STAGE_A(0, 1, 0);
  STAGE_B(0, 0, 0); STAGE_B(0, 1, 0);
  STAGE_B(1, 0, 1); STAGE_A(1, 0, 1);
  asm volatile("s_waitcnt vmcnt(4)" ::: "memory");   // tile0 landed; {B0,A0}(1) in flight
  __builtin_amdgcn_s_barrier();
  asm volatile("" ::: "memory");

#pragma unroll 1
  for (int t = 0; t < NKT; ++t) {
    const int p   = t & 1;
    const int ts1 = (t + 1 < NKT) ? t + 1 : NKT - 1;   // clamp: harmless re-stage
    const int ts2 = (t + 2 < NKT) ? t + 2 : NKT - 1;
    const int ar  = (p << 15) + (wm << 14);
    const int br  = 65536 + (p << 15) + ((wn >> 1) << 14) + ((wn & 1) << 13);

    short8 af[4][2], bf[4][2];

    // ===== phase 0: read A M0-3 + B N0-1 (12 ds_read_b128); stage A1(t+1)
#pragma unroll
    for (int mi = 0; mi < 4; ++mi) {
      af[mi][0] = *(const short8*)(smb + ar + mi * 2048 + abase);
      af[mi][1] = *(const short8*)(smb + ar + mi * 2048 + (abase ^ 64));
    }
#pragma unroll
    for (int ni = 0; ni < 2; ++ni) {
      bf[ni][0] = *(const short8*)(smb + br + ni * 2048 + abase);
      bf[ni][1] = *(const short8*)(smb + br + ni * 2048 + (abase ^ 64));
    }
    STAGE_A(p ^ 1, 1, ts1);
    PHASE_MID();
#pragma unroll
    for (int mi = 0; mi < 4; ++mi)
#pragma unroll
      for (int ni = 0; ni < 2; ++ni) MFMA2(acc[mi][ni], af[mi], bf[ni]);
    PHASE_END();

    // ===== phase 1: read B N2-3 (4 reads); stage B1(t+1); MFMA M0-3 x N2-3
#pragma unroll
    for (int ni = 2; ni < 4; ++ni) {
      bf[ni][0] = *(const short8*)(smb + br + ni * 2048 + abase);
      bf[ni][1] = *(const short8*)(smb + br + ni * 2048 + (abase ^ 64));
    }
    STAGE_B(p ^ 1, 1, ts1);
    PHASE_MID();
#pragma unroll
    for (int mi = 0; mi < 4; ++mi)
#pragma unroll
      for (int ni = 2; ni < 4; ++ni) MFMA2(acc[mi][ni], af[mi], bf[ni]);
    PHASE_END();

    // ===== phase 2: read A M4-7 (8 reads); stage B0(t+2); MFMA M4-7 x N0-1
    // (B(t) fully read as of ph1-end barrier -> B0(t+2) overwrite is safe)
#pragma unroll
    for (int mi = 0; mi < 4; ++mi) {
      af[mi][0] = *(const short8*)(smb + ar + (mi + 4) * 2048 + abase);
      af[mi][1] = *(const short8*)(smb + ar + (mi + 4) * 2048 + (abase ^ 64));
    }
    STAGE_B(p, 0, ts2);
    PHASE_MID();
#pragma unroll
    for (int mi = 0; mi < 4; ++mi)
#pragma unroll
      for (int ni = 0; ni < 2; ++ni) MFMA2(acc[mi + 4][ni], af[mi], bf[ni]);
    PHASE_END();

    // ===== phase 3: no reads; stage A0(t+2); MFMA M4-7 x N2-3; tile boundary
    // (A(t) fully read as of ph2-end barrier -> A0(t+2) overwrite is safe)
    STAGE_A(p, 0, ts2);
    PHASE_MID();
#pragma unroll
    for (int mi = 0; mi < 4; ++mi)
#pragma unroll
      for (int ni = 2; ni < 4; ++ni) MFMA2(acc[mi + 4][ni], af[mi], bf[ni]);
    PHASE_END_TILE();   // vmcnt(4): tile t+1 landed, {B0,A0}(t+2) in flight
  }

  // drain stray clamped stages before LDS dealloc / block retire
  asm volatile("s_waitcnt vmcnt(0)" ::: "memory");

  // ---- epilogue: C/D layout col = r, row = q*4 + i (verified m89/m91) ----
  const int r0 = bm + wm * 128;
  const int c0 = bn + wn * 64;
#pragma unroll
  for (int mi = 0; mi < 8; ++mi)
#pragma unroll
    for (int ni = 0; ni < 4; ++ni) {
      const int row0 = r0 + mi * 16 + q * 4;
      const int col  = c0 + ni * 16 + r;
#pragma unroll
      for (int i = 0; i < 4; ++i)
        C[(size_t)(row0 + i) * N + col] = acc[mi][ni][i];
    }
}

extern "C" void kernel_launch(void* const* d_in, const int* in_sizes, int n_in,
                              void* d_out, int out_size, void* d_ws, size_t ws_size,
                              hipStream_t stream) {
  const float* a    = (const float*)d_in[0];   // [4096, 4096] fp32
  const int*   hidx = (const int*)d_in[1];     // [4096, 4097] int32
  const float* W    = (const float*)d_in[2];   // [65536] fp32
  float*       out  = (float*)d_out;           // [4096, 4096] fp32

  // workspace: A_ext bf16 [B_DIM][KP] | Wv bf16 [FAN_OUT][KP]  (68.2 MB)
  unsigned short* Ae = (unsigned short*)d_ws;
  unsigned short* Wv = Ae + (size_t)B_DIM * KP;

  static bool attr_set = false;
  if (!attr_set) {
    hipFuncSetAttribute((const void*)gemm_bt8,
                        hipFuncAttributeMaxDynamicSharedMemorySize, 131072);
    attr_set = true;
  }

  build_aext<<<B_DIM, 256, 0, stream>>>(a, Ae);
  build_wv<<<FAN_OUT / 4, 512, 0, stream>>>(hidx, W, Wv);
  gemm_bt8<<<dim3(FAN_OUT / BN, B_DIM / BM), 512, 131072, stream>>>(Ae, Wv, out, B_DIM, FAN_OUT);
}

// Round 2
// 293.873 us; speedup vs baseline: 1.1600x; 1.0209x over previous
//
#include <hip/hip_runtime.h>
#include <hip/hip_bf16.h>
#include <stdint.h>

// Problem: out[b,i] = sum_j a_ext[b,j] * W[hash_idx[i,j]]
//   B=4096, FAN_IN=4096 (+1 bias col), FAN_OUT=4096, K-table=65536
// Strategy: materialize bf16 A_ext [B][KP] and Wv [FAN_OUT][KP] (K padded
// 4097->4160), then bf16 MFMA GEMM-BT into fp32 C.
// R2: build_wv = LDS-resident two-phase gather (64KB half-table in LDS).
// R7: single-barrier dbuf 128x128 gemm: 180us, MfmaUtil 34% (m97 ceiling).
// R8: WIN: 256x256 8-phase (m201-class), XOR swizzle both-sides: 128us,
//     1091 TF, conflicts 1.7e7 -> 0, MfmaUtil 46%. Landed at m198 level,
//     not m201 (1563): runtime buffer parity (#pragma unroll 1, p=t&1)
//     defeats immediate-offset folding + forces per-stage readfirstlane/M0
//     setup + conservative compiler waits. ~30% cycles unattributed stall.
// R9 (this): compile-time parity. Main loop = 32 x {tile(buf0), tile(buf1)}
//     via KTILE(P,...) macro (P literal); tile 64 peeled as barrier-free
//     tail (resident in buf0 after t=63 boundary vmcnt(4); outstanding
//     loads are clamped stale re-stages into buf1, drained by final
//     vmcnt(0)). Stage schedule/legality identical to R8 (harness-verified):
//       ph0: stage A1(t+1)->buf[P^1] | ph1: B1(t+1)->buf[P^1]
//       ph2: stage B0(t+2)->buf[P]   | ph3: A0(t+2)->buf[P]
//     Boundary PHASE_END_TILE: vmcnt(4) leaves exactly {B0,A0}(t+2) in
//     flight. Never vmcnt(0) in-loop.

#define B_DIM   4096
#define FAN_IN  4096
#define FAN_OUT 4096
#define KD      (FAN_IN + 1)   // 4097
#define KP      4160           // padded: 65 * 64
#define NKT     65             // K-tiles of BK=64

#define BM 256
#define BN 256
#define BK 64

typedef __attribute__((ext_vector_type(8))) short  short8;   // 8 bf16 = 4 VGPRs
typedef __attribute__((ext_vector_type(4))) float  floatx4;  // MFMA acc

__device__ __forceinline__ unsigned short f2bf(float f) {
  union { float f; unsigned u; } v; v.f = f;
  unsigned u = v.u;
  u += 0x7fffu + ((u >> 16) & 1u);   // round-to-nearest-even
  return (unsigned short)(u >> 16);
}

__device__ __forceinline__ void async16(const void* g, void* l) {
  // direct global->LDS DMA, 16B/lane; LDS dest = wave-uniform base + lane*16
  __builtin_amdgcn_global_load_lds(
      (const __attribute__((address_space(1))) void*)g,
      (__attribute__((address_space(3))) void*)l, 16, 0, 0);
}

// ---- Kernel 1: A_ext[b][j] = bf16(a[b][j]); col 4096 = 1.0; cols 4097..KP-1 = 0
__global__ __launch_bounds__(256) void build_aext(
    const float* __restrict__ a, unsigned short* __restrict__ Ae) {
  const int row = blockIdx.x;
  const float* ar = a + (size_t)row * FAN_IN;
  unsigned short* er = Ae + (size_t)row * KP;
  for (int j4 = threadIdx.x; j4 < KP / 4; j4 += 256) {
    const int j = j4 * 4;
    float x0, x1, x2, x3;
    if (j + 3 < FAN_IN) {
      const float4 v = *(const float4*)(ar + j);   // 16B-aligned (row stride 16KB)
      x0 = v.x; x1 = v.y; x2 = v.z; x3 = v.w;
    } else {
      x0 = (j + 0 < FAN_IN) ? ar[j + 0] : ((j + 0 == FAN_IN) ? 1.0f : 0.0f);
      x1 = (j + 1 < FAN_IN) ? ar[j + 1] : ((j + 1 == FAN_IN) ? 1.0f : 0.0f);
      x2 = (j + 2 < FAN_IN) ? ar[j + 2] : ((j + 2 == FAN_IN) ? 1.0f : 0.0f);
      x3 = (j + 3 < FAN_IN) ? ar[j + 3] : ((j + 3 == FAN_IN) ? 1.0f : 0.0f);
    }
    ushort4 o;
    o.x = f2bf(x0); o.y = f2bf(x1); o.z = f2bf(x2); o.w = f2bf(x3);
    *(ushort4*)(er + j) = o;   // 8B store, aligned
  }
}

// ---- Kernel 2 (R2 version, measured-best): Wv[i][j] = bf16(W[hash_idx[i][j]]).
__global__ __launch_bounds__(512) void build_wv(
    const int* __restrict__ hidx, const float* __restrict__ W,
    unsigned short* __restrict__ Wv) {
  __shared__ unsigned short wl[32768];   // 64 KB: half of W as bf16
  const int t  = threadIdx.x;
  const int r0 = blockIdx.x * 4;

  int          idx[4][9];
  unsigned short res[4][9];
#pragma unroll
  for (int row = 0; row < 4; row++) {
    const int* hr = hidx + (size_t)(r0 + row) * KD;
#pragma unroll
    for (int i = 0; i < 9; i++) {
      const int j = i * 512 + t;
      idx[row][i] = (j < KD) ? hr[j] : 0;
      res[row][i] = 0;
    }
  }

  for (int h = 0; h < 2; h++) {
    __syncthreads();   // protect phase-0 reads before phase-1 refill
    const float4* Wb = (const float4*)(W + h * 32768);
#pragma unroll
    for (int i = 0; i < 16; i++) {
      const int f4 = i * 512 + t;
      const float4 v = Wb[f4];
      ushort4 o;
      o.x = f2bf(v.x); o.y = f2bf(v.y); o.z = f2bf(v.z); o.w = f2bf(v.w);
      *(ushort4*)&wl[f4 * 4] = o;
    }
    __syncthreads();
    const int lo = h << 15;
#pragma unroll
    for (int row = 0; row < 4; row++)
#pragma unroll
      for (int i = 0; i < 9; i++) {
        const int v = idx[row][i];
        if ((v & 32768) == lo)
          res[row][i] = wl[v & 32767];
      }
  }

#pragma unroll
  for (int row = 0; row < 4; row++) {
    unsigned short* wr = Wv + (size_t)(r0 + row) * KP;
#pragma unroll
    for (int i = 0; i < 9; i++) {
      const int j = i * 512 + t;
      if (j < KD) wr[j] = res[row][i];
    }
    if (t < KP - KD) wr[KD + t] = 0;
  }
}

// ---- Kernel 3 (R9): 256x256 8-phase GEMM-BT, compile-time-parity unrolled.
// LDS layout (bytes, 128KB dynamic): A: buf*32768 + half*16384 + row*128 + slot*16
//   with physical slot = logical_slot ^ (row&7)  (slot = 16B chunk, 8 per row)
// B region at +65536, same layout.
// Stage half-tile (128 rows x 64 k): 2 calls/wave, wave w writes rows
//   c*64 + w*8 + (lane>>3), phys slot lane&7 carrying logical slot (lane&7)^(lane>>3).

#define STAGE_A(BUF, H, KOFF)                                                      \
  do {                                                                             \
    async16(pa + ((H) * 128 + 0)  * KP + (KOFF),                                   \
            smb + ((BUF) << 15) + ((H) << 14) + dA);                               \
    async16(pa + ((H) * 128 + 64) * KP + (KOFF),                                   \
            smb + ((BUF) << 15) + ((H) << 14) + 8192 + dA);                        \
  } while (0)

#define STAGE_B(BUF, H, KOFF)                                                      \
  do {                                                                             \
    async16(pb + ((H) * 128 + 0)  * KP + (KOFF),                                   \
            smb + 65536 + ((BUF) << 15) + ((H) << 14) + dA);                       \
    async16(pb + ((H) * 128 + 64) * KP + (KOFF),                                   \
            smb + 65536 + ((BUF) << 15) + ((H) << 14) + 8192 + dA);                \
  } while (0)

#define PHASE_MID()                                                                \
  do {                                                                             \
    asm volatile("" ::: "memory");                                                 \
    __builtin_amdgcn_s_barrier();                                                  \
    asm volatile("s_waitcnt lgkmcnt(0)" ::: "memory");                             \
    __builtin_amdgcn_sched_barrier(0);                                             \
    __builtin_amdgcn_s_setprio(1);                                                 \
  } while (0)

#define PHASE_END()                                                                \
  do {                                                                             \
    __builtin_amdgcn_s_setprio(0);                                                 \
    asm volatile("" ::: "memory");                                                 \
    __builtin_amdgcn_s_barrier();                                                  \
    asm volatile("" ::: "memory");                                                 \
  } while (0)

#define PHASE_END_TILE()                                                           \
  do {                                                                             \
    __builtin_amdgcn_s_setprio(0);                                                 \
    asm volatile("s_waitcnt vmcnt(4)" ::: "memory");                               \
    __builtin_amdgcn_s_barrier();                                                  \
    asm volatile("" ::: "memory");                                                 \
  } while (0)

#define MFMA2(ACC, AF, BF)                                                         \
  do {                                                                             \
    ACC = __builtin_amdgcn_mfma_f32_16x16x32_bf16((AF)[0], (BF)[0], ACC, 0, 0, 0); \
    ACC = __builtin_amdgcn_mfma_f32_16x16x32_bf16((AF)[1], (BF)[1], ACC, 0, 0, 0); \
  } while (0)

// One K-tile with compile-time buffer parity P. K1/K2 are element k-offsets
// (ts1*64, ts2*64, pre-clamped to <= 4096) of the tiles being staged.
#define KTILE(P, K1, K2)                                                           \
  do {                                                                             \
    short8 af[4][2], bf[4][2];                                                     \
    /* phase 0: read A M0-3 + B N0-1 (12 b128); stage A1(t+1) */                   \
    _Pragma("unroll")                                                              \
    for (int mi = 0; mi < 4; ++mi) {                                               \
      af[mi][0] = *(const short8*)(smb + ((P) << 15) + arB + mi * 2048 + abase);   \
      af[mi][1] = *(const short8*)(smb + ((P) << 15) + arB + mi * 2048 + (abase ^ 64)); \
    }                                                                              \
    _Pragma("unroll")                                                              \
    for (int ni = 0; ni < 2; ++ni) {                                               \
      bf[ni][0] = *(const short8*)(smb + ((P) << 15) + brB + ni * 2048 + abase);   \
      bf[ni][1] = *(const short8*)(smb + ((P) << 15) + brB + ni * 2048 + (abase ^ 64)); \
    }                                                                              \
    STAGE_A((P) ^ 1, 1, K1);                                                       \
    PHASE_MID();                                                                   \
    _Pragma("unroll")                                                              \
    for (int mi = 0; mi < 4; ++mi)                                                 \
      _Pragma("unroll")                                                            \
      for (int ni = 0; ni < 2; ++ni) MFMA2(acc[mi][ni], af[mi], bf[ni]);           \
    PHASE_END();                                                                   \
    /* phase 1: read B N2-3 (4 b128); stage B1(t+1); MFMA M0-3 x N2-3 */           \
    _Pragma("unroll")                                                              \
    for (int ni = 2; ni < 4; ++ni) {                                               \
      bf[ni][0] = *(const short8*)(smb + ((P) << 15) + brB + ni * 2048 + abase);   \
      bf[ni][1] = *(const short8*)(smb + ((P) << 15) + brB + ni * 2048 + (abase ^ 64)); \
    }                                                                              \
    STAGE_B((P) ^ 1, 1, K1);                                                       \
    PHASE_MID();                                                                   \
    _Pragma("unroll")                                                              \
    for (int mi = 0; mi < 4; ++mi)                                                 \
      _Pragma("unroll")                                                            \
      for (int ni = 2; ni < 4; ++ni) MFMA2(acc[mi][ni], af[mi], bf[ni]);           \
    PHASE_END();                                                                   \
    /* phase 2: read A M4-7 (8 b128); stage B0(t+2); MFMA M4-7 x N0-1 */           \
    /* (B(t) fully read as of ph1-end barrier -> B0(t+2) overwrite safe) */        \
    _Pragma("unroll")                                                              \
    for (int mi = 0; mi < 4; ++mi) {                                               \
      af[mi][0] = *(const short8*)(smb + ((P) << 15) + arB + (mi + 4) * 2048 + abase); \
      af[mi][1] = *(const short8*)(smb + ((P) << 15) + arB + (mi + 4) * 2048 + (abase ^ 64)); \
    }                                                                              \
    STAGE_B((P), 0, K2);                                                           \
    PHASE_MID();                                                                   \
    _Pragma("unroll")                                                              \
    for (int mi = 0; mi < 4; ++mi)                                                 \
      _Pragma("unroll")                                                            \
      for (int ni = 0; ni < 2; ++ni) MFMA2(acc[mi + 4][ni], af[mi], bf[ni]);       \
    PHASE_END();                                                                   \
    /* phase 3: no reads; stage A0(t+2); MFMA M4-7 x N2-3; tile boundary */        \
    /* (A(t) fully read as of ph2-end barrier -> A0(t+2) overwrite safe) */        \
    STAGE_A((P), 0, K2);                                                           \
    PHASE_MID();                                                                   \
    _Pragma("unroll")                                                              \
    for (int mi = 0; mi < 4; ++mi)                                                 \
      _Pragma("unroll")                                                            \
      for (int ni = 2; ni < 4; ++ni) MFMA2(acc[mi + 4][ni], af[mi], bf[ni]);       \
    PHASE_END_TILE(); /* vmcnt(4): tile t+1 landed, {B0,A0}(t+2) in flight */      \
  } while (0)

__global__ __launch_bounds__(512, 2) void gemm_bt8(
    const unsigned short* __restrict__ A, const unsigned short* __restrict__ Bm,
    float* __restrict__ C, int M, int N) {
  extern __shared__ char smb[];   // 128 KB
  const int tid = threadIdx.x;
  const int l   = tid & 63;
  const int w   = tid >> 6;       // 8 waves
  const int wm  = w >> 2;         // 0..1  (M half: rows wm*128..+127)
  const int wn  = w & 3;          // 0..3  (N 64-col strip)
  const int bm  = blockIdx.y * BM;
  const int bn  = blockIdx.x * BN;
  const int q   = l >> 4;         // MFMA k-quad
  const int r   = l & 15;         // MFMA m/n-in-16

  // ---- staging source pointers (pre-swizzled global column) ----
  const int lrow = l >> 3;                       // 0..7 (row-in-8)
  const int lcol = ((l & 7) ^ lrow) * 8;         // swizzled 16B chunk (elements)
  const unsigned short* pa = A  + (size_t)(bm + w * 8 + lrow) * KP + lcol;
  const unsigned short* pb = Bm + (size_t)(bn + w * 8 + lrow) * KP + lcol;
  const int dA = w * 1024;                       // wave's byte base in 8KB slab

  // ---- swizzled ds_read byte offset (within a 16KB half region) ----
  // logical: row = mi*16 + r, slot = ks*4 + q; physical slot ^= (r&7)
  const int abase = r * 128 + ((q ^ (r & 7)) << 4);   // ks=0; ks=1 is ^64
  const int arB   = wm << 14;                         // A half base (sans buf bit)
  const int brB   = 65536 + ((wn >> 1) << 14) + ((wn & 1) << 13);  // B slab base

  floatx4 acc[8][4] = {};

  // ---- prologue: tile0 -> buf0 (all 4 halves), then B0(1), A0(1) -> buf1 ----
  STAGE_A(0, 0, 0); STAGE_A(0, 1, 0);
  STAGE_B(0, 0, 0); STAGE_B(0, 1, 0);
  STAGE_B(1, 0, 64); STAGE_A(1, 0, 64);
  asm volatile("s_waitcnt vmcnt(4)" ::: "memory");   // tile0 landed; {B0,A0}(1) in flight
  __builtin_amdgcn_s_barrier();
  asm volatile("" ::: "memory");

  // ---- main loop: tiles 0..63 as 32 compile-time-parity pairs ----
  // iter tt: tile 2tt  (P=0): ts1=2tt+1 -> k1,        ts2=2tt+2 -> k2
  //          tile 2tt+1(P=1): ts1=2tt+2 -> k2,        ts2=2tt+3 -> k2+64
  // clamp stage offsets to 4096 (tile 64); clamped re-stages are harmless
  // (they re-write a tile-64 half into the buffer they already occupy or a
  // dead buffer; drained by boundary/final waits).
  int k1 = 64, k2 = 128;
#pragma unroll 1
  for (int tt = 0; tt < 32; ++tt) {
    const int k2c = (k2 > 4096) ? 4096 : k2;
    const int k3c = (k2 + 64 > 4096) ? 4096 : k2 + 64;
    KTILE(0, k1, k2c);
    KTILE(1, k2c, k3c);
    k1 += 128; k2 += 128;
  }

  // ---- tail: tile 64 (buf0), fully resident after t=63 boundary vmcnt(4).
  // Outstanding loads are stale clamped re-stages into buf1 -> no hazard with
  // buf0 reads; no barriers needed (per-wave data dep only).
  {
    short8 af[8][2], bf[4][2];
#pragma unroll
    for (int mi = 0; mi < 8; ++mi) {
      af[mi][0] = *(const short8*)(smb + arB + mi * 2048 + abase);
      af[mi][1] = *(const short8*)(smb + arB + mi * 2048 + (abase ^ 64));
    }
#pragma unroll
    for (int ni = 0; ni < 4; ++ni) {
      bf[ni][0] = *(const short8*)(smb + brB + ni * 2048 + abase);
      bf[ni][1] = *(const short8*)(smb + brB + ni * 2048 + (abase ^ 64));
    }
    asm volatile("s_waitcnt lgkmcnt(0)" ::: "memory");
    __builtin_amdgcn_sched_barrier(0);
    __builtin_amdgcn_s_setprio(1);
#pragma unroll
    for (int mi = 0; mi < 8; ++mi)
#pragma unroll
      for (int ni = 0; ni < 4; ++ni) MFMA2(acc[mi][ni], af[mi], bf[ni]);
    __builtin_amdgcn_s_setprio(0);
  }

  // drain stray clamped stages before LDS dealloc / block retire
  asm volatile("s_waitcnt vmcnt(0)" ::: "memory");

  // ---- epilogue: C/D layout col = r, row = q*4 + i (verified m89/m91) ----
  const int r0 = bm + wm * 128;
  const int c0 = bn + wn * 64;
#pragma unroll
  for (int mi = 0; mi < 8; ++mi)
#pragma unroll
    for (int ni = 0; ni < 4; ++ni) {
      const int row0 = r0 + mi * 16 + q * 4;
      const int col  = c0 + ni * 16 + r;
#pragma unroll
      for (int i = 0; i < 4; ++i)
        C[(size_t)(row0 + i) * N + col] = acc[mi][ni][i];
    }
}

extern "C" void kernel_launch(void* const* d_in, const int* in_sizes, int n_in,
                              void* d_out, int out_size, void* d_ws, size_t ws_size,
                              hipStream_t stream) {
  const float* a    = (const float*)d_in[0];   // [4096, 4096] fp32
  const int*   hidx = (const int*)d_in[1];     // [4096, 4097] int32
  const float* W    = (const float*)d_in[2];   // [65536] fp32
  float*       out  = (float*)d_out;           // [4096, 4096] fp32

  // workspace: A_ext bf16 [B_DIM][KP] | Wv bf16 [FAN_OUT][KP]  (68.2 MB)
  unsigned short* Ae = (unsigned short*)d_ws;
  unsigned short* Wv = Ae + (size_t)B_DIM * KP;

  static bool attr_set = false;
  if (!attr_set) {
    hipFuncSetAttribute((const void*)gemm_bt8,
                        hipFuncAttributeMaxDynamicSharedMemorySize, 131072);
    attr_set = true;
  }

  build_aext<<<B_DIM, 256, 0, stream>>>(a, Ae);
  build_wv<<<FAN_OUT / 4, 512, 0, stream>>>(hidx, W, Wv);
  gemm_bt8<<<dim3(FAN_OUT / BN, B_DIM / BM), 512, 131072, stream>>>(Ae, Wv, out, B_DIM, FAN_OUT);
}

// Round 3
// 284.988 us; speedup vs baseline: 1.1962x; 1.0312x over previous
//
#include <hip/hip_runtime.h>
#include <hip/hip_bf16.h>
#include <stdint.h>

// Problem: out[b,i] = sum_j a_ext[b,j] * W[hash_idx[i,j]]
//   B=4096, FAN_IN=4096 (+1 bias col), FAN_OUT=4096, K-table=65536
// Strategy: materialize bf16 A_ext [B][KP] and Wv [FAN_OUT][KP] (K padded
// 4097->4160), then bf16 MFMA GEMM-BT into fp32 C.
// R7: single-barrier dbuf 128x128 gemm: 180us, MfmaUtil 34% (m97 ceiling).
// R8: WIN: 256x256 8-phase (m201-class), XOR swizzle both-sides: 128us,
//     conflicts 1.7e7 -> 0, MfmaUtil 46%.
// R9: WIN: compile-time buffer parity (32 x unrolled {buf0,buf1} pairs,
//     peeled tail): 118.6us, 1177 TF, MfmaUtil 51, VALU 17. Gemm parked —
//     remaining gap to m201 is addressing micro-opt (m203: mostly null).
// R10 (this): prep is now dominant (total 294 - gemm 119 = ~175us, while
//     theory floor for prep is ~45us). Rewrite build_wv: single-pass
//     FULL-table LDS gather (65536 bf16 = 128KB dynamic LDS, 1 block/CU,
//     256 blocks x 1024 thr, 16 rows/block). Kills: 2-phase double pass,
//     72 divergent residency checks/thread, 36-reg idx/res arrays, scalar
//     2B stores. build_aext + gemm byte-identical to R9 (verified).

#define B_DIM   4096
#define FAN_IN  4096
#define FAN_OUT 4096
#define KD      (FAN_IN + 1)   // 4097
#define KP      4160           // padded: 65 * 64
#define NKT     65             // K-tiles of BK=64

#define BM 256
#define BN 256
#define BK 64

typedef __attribute__((ext_vector_type(8))) short  short8;   // 8 bf16 = 4 VGPRs
typedef __attribute__((ext_vector_type(4))) float  floatx4;  // MFMA acc

__device__ __forceinline__ unsigned short f2bf(float f) {
  union { float f; unsigned u; } v; v.f = f;
  unsigned u = v.u;
  u += 0x7fffu + ((u >> 16) & 1u);   // round-to-nearest-even
  return (unsigned short)(u >> 16);
}

__device__ __forceinline__ void async16(const void* g, void* l) {
  // direct global->LDS DMA, 16B/lane; LDS dest = wave-uniform base + lane*16
  __builtin_amdgcn_global_load_lds(
      (const __attribute__((address_space(1))) void*)g,
      (__attribute__((address_space(3))) void*)l, 16, 0, 0);
}

// ---- Kernel 1: A_ext[b][j] = bf16(a[b][j]); col 4096 = 1.0; cols 4097..KP-1 = 0
__global__ __launch_bounds__(256) void build_aext(
    const float* __restrict__ a, unsigned short* __restrict__ Ae) {
  const int row = blockIdx.x;
  const float* ar = a + (size_t)row * FAN_IN;
  unsigned short* er = Ae + (size_t)row * KP;
  for (int j4 = threadIdx.x; j4 < KP / 4; j4 += 256) {
    const int j = j4 * 4;
    float x0, x1, x2, x3;
    if (j + 3 < FAN_IN) {
      const float4 v = *(const float4*)(ar + j);   // 16B-aligned (row stride 16KB)
      x0 = v.x; x1 = v.y; x2 = v.z; x3 = v.w;
    } else {
      x0 = (j + 0 < FAN_IN) ? ar[j + 0] : ((j + 0 == FAN_IN) ? 1.0f : 0.0f);
      x1 = (j + 1 < FAN_IN) ? ar[j + 1] : ((j + 1 == FAN_IN) ? 1.0f : 0.0f);
      x2 = (j + 2 < FAN_IN) ? ar[j + 2] : ((j + 2 == FAN_IN) ? 1.0f : 0.0f);
      x3 = (j + 3 < FAN_IN) ? ar[j + 3] : ((j + 3 == FAN_IN) ? 1.0f : 0.0f);
    }
    ushort4 o;
    o.x = f2bf(x0); o.y = f2bf(x1); o.z = f2bf(x2); o.w = f2bf(x3);
    *(ushort4*)(er + j) = o;   // 8B store, aligned
  }
}

// ---- Kernel 2 (R10): Wv[i][j] = bf16(W[hash_idx[i][j]]).
// Single pass: ENTIRE W as bf16 in 128KB dynamic LDS (1 block/CU).
// 256 blocks x 1024 threads, 16 rows/block. Per row, thread t handles
// j in [4t, 4t+4): 4 coalesced idx loads (lane-stride 16B, full line use
// across the 4 loads) -> 4 ds_read_u16 gathers (random, ~6cyc/wave, cheap)
// -> one 8B ushort4 store. Threads 0..63 handle col 4096 + the 63 pad zeros.
__global__ __launch_bounds__(1024) void build_wv(
    const int* __restrict__ hidx, const float* __restrict__ W,
    unsigned short* __restrict__ Wv) {
  extern __shared__ unsigned short wl[];   // 65536 bf16 = 128 KB
  const int t = threadIdx.x;

  // Fill: 65536 floats -> bf16. 16 x (float4 load + 4 cvt + ushort4 LDS store).
  const float4* Wf = (const float4*)W;
#pragma unroll
  for (int i = 0; i < 16; i++) {
    const int f4 = i * 1024 + t;
    const float4 v = Wf[f4];
    ushort4 o;
    o.x = f2bf(v.x); o.y = f2bf(v.y); o.z = f2bf(v.z); o.w = f2bf(v.w);
    *(ushort4*)&wl[f4 * 4] = o;   // byte addr f4*8: 8B aligned, 2-way alias free
  }
  __syncthreads();

  const int r0 = blockIdx.x * 16;
#pragma unroll 4
  for (int r = 0; r < 16; r++) {
    const int* hr = hidx + (size_t)(r0 + r) * KD;
    unsigned short* wr = Wv + (size_t)(r0 + r) * KP;
    const int j = 4 * t;                    // 0..4092: covers cols 0..4095
    ushort4 o;
    o.x = wl[hr[j + 0]];
    o.y = wl[hr[j + 1]];
    o.z = wl[hr[j + 2]];
    o.w = wl[hr[j + 3]];
    *(ushort4*)(wr + j) = o;                // 8B store, aligned (row base 8320B)
    if (t < 64)                             // col 4096 + pad 4097..4159 = 0
      wr[4096 + t] = (t == 0) ? wl[hr[4096]] : (unsigned short)0;
  }
}

// ---- Kernel 3 (R9, verified): 256x256 8-phase GEMM-BT, compile-time parity.
// LDS layout (bytes, 128KB dynamic): A: buf*32768 + half*16384 + row*128 + slot*16
//   with physical slot = logical_slot ^ (row&7)  (slot = 16B chunk, 8 per row)
// B region at +65536, same layout.
// Stage half-tile (128 rows x 64 k): 2 calls/wave, wave w writes rows
//   c*64 + w*8 + (lane>>3), phys slot lane&7 carrying logical slot (lane&7)^(lane>>3).

#define STAGE_A(BUF, H, KOFF)                                                      \
  do {                                                                             \
    async16(pa + ((H) * 128 + 0)  * KP + (KOFF),                                   \
            smb + ((BUF) << 15) + ((H) << 14) + dA);                               \
    async16(pa + ((H) * 128 + 64) * KP + (KOFF),                                   \
            smb + ((BUF) << 15) + ((H) << 14) + 8192 + dA);                        \
  } while (0)

#define STAGE_B(BUF, H, KOFF)                                                      \
  do {                                                                             \
    async16(pb + ((H) * 128 + 0)  * KP + (KOFF),                                   \
            smb + 65536 + ((BUF) << 15) + ((H) << 14) + dA);                       \
    async16(pb + ((H) * 128 + 64) * KP + (KOFF),                                   \
            smb + 65536 + ((BUF) << 15) + ((H) << 14) + 8192 + dA);                \
  } while (0)

#define PHASE_MID()                                                                \
  do {                                                                             \
    asm volatile("" ::: "memory");                                                 \
    __builtin_amdgcn_s_barrier();                                                  \
    asm volatile("s_waitcnt lgkmcnt(0)" ::: "memory");                             \
    __builtin_amdgcn_sched_barrier(0);                                             \
    __builtin_amdgcn_s_setprio(1);                                                 \
  } while (0)

#define PHASE_END()                                                                \
  do {                                                                             \
    __builtin_amdgcn_s_setprio(0);                                                 \
    asm volatile("" ::: "memory");                                                 \
    __builtin_amdgcn_s_barrier();                                                  \
    asm volatile("" ::: "memory");                                                 \
  } while (0)

#define PHASE_END_TILE()                                                           \
  do {                                                                             \
    __builtin_amdgcn_s_setprio(0);                                                 \
    asm volatile("s_waitcnt vmcnt(4)" ::: "memory");                               \
    __builtin_amdgcn_s_barrier();                                                  \
    asm volatile("" ::: "memory");                                                 \
  } while (0)

#define MFMA2(ACC, AF, BF)                                                         \
  do {                                                                             \
    ACC = __builtin_amdgcn_mfma_f32_16x16x32_bf16((AF)[0], (BF)[0], ACC, 0, 0, 0); \
    ACC = __builtin_amdgcn_mfma_f32_16x16x32_bf16((AF)[1], (BF)[1], ACC, 0, 0, 0); \
  } while (0)

// One K-tile with compile-time buffer parity P. K1/K2 are element k-offsets
// (ts1*64, ts2*64, pre-clamped to <= 4096) of the tiles being staged.
#define KTILE(P, K1, K2)                                                           \
  do {                                                                             \
    short8 af[4][2], bf[4][2];                                                     \
    /* phase 0: read A M0-3 + B N0-1 (12 b128); stage A1(t+1) */                   \
    _Pragma("unroll")                                                              \
    for (int mi = 0; mi < 4; ++mi) {                                               \
      af[mi][0] = *(const short8*)(smb + ((P) << 15) + arB + mi * 2048 + abase);   \
      af[mi][1] = *(const short8*)(smb + ((P) << 15) + arB + mi * 2048 + (abase ^ 64)); \
    }                                                                              \
    _Pragma("unroll")                                                              \
    for (int ni = 0; ni < 2; ++ni) {                                               \
      bf[ni][0] = *(const short8*)(smb + ((P) << 15) + brB + ni * 2048 + abase);   \
      bf[ni][1] = *(const short8*)(smb + ((P) << 15) + brB + ni * 2048 + (abase ^ 64)); \
    }                                                                              \
    STAGE_A((P) ^ 1, 1, K1);                                                       \
    PHASE_MID();                                                                   \
    _Pragma("unroll")                                                              \
    for (int mi = 0; mi < 4; ++mi)                                                 \
      _Pragma("unroll")                                                            \
      for (int ni = 0; ni < 2; ++ni) MFMA2(acc[mi][ni], af[mi], bf[ni]);           \
    PHASE_END();                                                                   \
    /* phase 1: read B N2-3 (4 b128); stage B1(t+1); MFMA M0-3 x N2-3 */           \
    _Pragma("unroll")                                                              \
    for (int ni = 2; ni < 4; ++ni) {                                               \
      bf[ni][0] = *(const short8*)(smb + ((P) << 15) + brB + ni * 2048 + abase);   \
      bf[ni][1] = *(const short8*)(smb + ((P) << 15) + brB + ni * 2048 + (abase ^ 64)); \
    }                                                                              \
    STAGE_B((P) ^ 1, 1, K1);                                                       \
    PHASE_MID();                                                                   \
    _Pragma("unroll")                                                              \
    for (int mi = 0; mi < 4; ++mi)                                                 \
      _Pragma("unroll")                                                            \
      for (int ni = 2; ni < 4; ++ni) MFMA2(acc[mi][ni], af[mi], bf[ni]);           \
    PHASE_END();                                                                   \
    /* phase 2: read A M4-7 (8 b128); stage B0(t+2); MFMA M4-7 x N0-1 */           \
    /* (B(t) fully read as of ph1-end barrier -> B0(t+2) overwrite safe) */        \
    _Pragma("unroll")                                                              \
    for (int mi = 0; mi < 4; ++mi) {                                               \
      af[mi][0] = *(const short8*)(smb + ((P) << 15) + arB + (mi + 4) * 2048 + abase); \
      af[mi][1] = *(const short8*)(smb + ((P) << 15) + arB + (mi + 4) * 2048 + (abase ^ 64)); \
    }                                                                              \
    STAGE_B((P), 0, K2);                                                           \
    PHASE_MID();                                                                   \
    _Pragma("unroll")                                                              \
    for (int mi = 0; mi < 4; ++mi)                                                 \
      _Pragma("unroll")                                                            \
      for (int ni = 0; ni < 2; ++ni) MFMA2(acc[mi + 4][ni], af[mi], bf[ni]);       \
    PHASE_END();                                                                   \
    /* phase 3: no reads; stage A0(t+2); MFMA M4-7 x N2-3; tile boundary */        \
    /* (A(t) fully read as of ph2-end barrier -> A0(t+2) overwrite safe) */        \
    STAGE_A((P), 0, K2);                                                           \
    PHASE_MID();                                                                   \
    _Pragma("unroll")                                                              \
    for (int mi = 0; mi < 4; ++mi)                                                 \
      _Pragma("unroll")                                                            \
      for (int ni = 2; ni < 4; ++ni) MFMA2(acc[mi + 4][ni], af[mi], bf[ni]);       \
    PHASE_END_TILE(); /* vmcnt(4): tile t+1 landed, {B0,A0}(t+2) in flight */      \
  } while (0)

__global__ __launch_bounds__(512, 2) void gemm_bt8(
    const unsigned short* __restrict__ A, const unsigned short* __restrict__ Bm,
    float* __restrict__ C, int M, int N) {
  extern __shared__ char smb[];   // 128 KB
  const int tid = threadIdx.x;
  const int l   = tid & 63;
  const int w   = tid >> 6;       // 8 waves
  const int wm  = w >> 2;         // 0..1  (M half: rows wm*128..+127)
  const int wn  = w & 3;          // 0..3  (N 64-col strip)
  const int bm  = blockIdx.y * BM;
  const int bn  = blockIdx.x * BN;
  const int q   = l >> 4;         // MFMA k-quad
  const int r   = l & 15;         // MFMA m/n-in-16

  // ---- staging source pointers (pre-swizzled global column) ----
  const int lrow = l >> 3;                       // 0..7 (row-in-8)
  const int lcol = ((l & 7) ^ lrow) * 8;         // swizzled 16B chunk (elements)
  const unsigned short* pa = A  + (size_t)(bm + w * 8 + lrow) * KP + lcol;
  const unsigned short* pb = Bm + (size_t)(bn + w * 8 + lrow) * KP + lcol;
  const int dA = w * 1024;                       // wave's byte base in 8KB slab

  // ---- swizzled ds_read byte offset (within a 16KB half region) ----
  // logical: row = mi*16 + r, slot = ks*4 + q; physical slot ^= (r&7)
  const int abase = r * 128 + ((q ^ (r & 7)) << 4);   // ks=0; ks=1 is ^64
  const int arB   = wm << 14;                         // A half base (sans buf bit)
  const int brB   = 65536 + ((wn >> 1) << 14) + ((wn & 1) << 13);  // B slab base

  floatx4 acc[8][4] = {};

  // ---- prologue: tile0 -> buf0 (all 4 halves), then B0(1), A0(1) -> buf1 ----
  STAGE_A(0, 0, 0); STAGE_A(0, 1, 0);
  STAGE_B(0, 0, 0); STAGE_B(0, 1, 0);
  STAGE_B(1, 0, 64); STAGE_A(1, 0, 64);
  asm volatile("s_waitcnt vmcnt(4)" ::: "memory");   // tile0 landed; {B0,A0}(1) in flight
  __builtin_amdgcn_s_barrier();
  asm volatile("" ::: "memory");

  // ---- main loop: tiles 0..63 as 32 compile-time-parity pairs ----
  // iter tt: tile 2tt  (P=0): ts1=2tt+1 -> k1,        ts2=2tt+2 -> k2
  //          tile 2tt+1(P=1): ts1=2tt+2 -> k2,        ts2=2tt+3 -> k2+64
  // clamp stage offsets to 4096 (tile 64); clamped re-stages are harmless
  // (they re-write a tile-64 half into the buffer they already occupy or a
  // dead buffer; drained by boundary/final waits).
  int k1 = 64, k2 = 128;
#pragma unroll 1
  for (int tt = 0; tt < 32; ++tt) {
    const int k2c = (k2 > 4096) ? 4096 : k2;
    const int k3c = (k2 + 64 > 4096) ? 4096 : k2 + 64;
    KTILE(0, k1, k2c);
    KTILE(1, k2c, k3c);
    k1 += 128; k2 += 128;
  }

  // ---- tail: tile 64 (buf0), fully resident after t=63 boundary vmcnt(4).
  // Outstanding loads are stale clamped re-stages into buf1 -> no hazard with
  // buf0 reads; no barriers needed (per-wave data dep only).
  {
    short8 af[8][2], bf[4][2];
#pragma unroll
    for (int mi = 0; mi < 8; ++mi) {
      af[mi][0] = *(const short8*)(smb + arB + mi * 2048 + abase);
      af[mi][1] = *(const short8*)(smb + arB + mi * 2048 + (abase ^ 64));
    }
#pragma unroll
    for (int ni = 0; ni < 4; ++ni) {
      bf[ni][0] = *(const short8*)(smb + brB + ni * 2048 + abase);
      bf[ni][1] = *(const short8*)(smb + brB + ni * 2048 + (abase ^ 64));
    }
    asm volatile("s_waitcnt lgkmcnt(0)" ::: "memory");
    __builtin_amdgcn_sched_barrier(0);
    __builtin_amdgcn_s_setprio(1);
#pragma unroll
    for (int mi = 0; mi < 8; ++mi)
#pragma unroll
      for (int ni = 0; ni < 4; ++ni) MFMA2(acc[mi][ni], af[mi], bf[ni]);
    __builtin_amdgcn_s_setprio(0);
  }

  // drain stray clamped stages before LDS dealloc / block retire
  asm volatile("s_waitcnt vmcnt(0)" ::: "memory");

  // ---- epilogue: C/D layout col = r, row = q*4 + i (verified m89/m91) ----
  const int r0 = bm + wm * 128;
  const int c0 = bn + wn * 64;
#pragma unroll
  for (int mi = 0; mi < 8; ++mi)
#pragma unroll
    for (int ni = 0; ni < 4; ++ni) {
      const int row0 = r0 + mi * 16 + q * 4;
      const int col  = c0 + ni * 16 + r;
#pragma unroll
      for (int i = 0; i < 4; ++i)
        C[(size_t)(row0 + i) * N + col] = acc[mi][ni][i];
    }
}

extern "C" void kernel_launch(void* const* d_in, const int* in_sizes, int n_in,
                              void* d_out, int out_size, void* d_ws, size_t ws_size,
                              hipStream_t stream) {
  const float* a    = (const float*)d_in[0];   // [4096, 4096] fp32
  const int*   hidx = (const int*)d_in[1];     // [4096, 4097] int32
  const float* W    = (const float*)d_in[2];   // [65536] fp32
  float*       out  = (float*)d_out;           // [4096, 4096] fp32

  // workspace: A_ext bf16 [B_DIM][KP] | Wv bf16 [FAN_OUT][KP]  (68.2 MB)
  unsigned short* Ae = (unsigned short*)d_ws;
  unsigned short* Wv = Ae + (size_t)B_DIM * KP;

  static bool attr_set = false;
  if (!attr_set) {
    hipFuncSetAttribute((const void*)gemm_bt8,
                        hipFuncAttributeMaxDynamicSharedMemorySize, 131072);
    hipFuncSetAttribute((const void*)build_wv,
                        hipFuncAttributeMaxDynamicSharedMemorySize, 131072);
    attr_set = true;
  }

  build_aext<<<B_DIM, 256, 0, stream>>>(a, Ae);
  build_wv<<<FAN_OUT / 16, 1024, 131072, stream>>>(hidx, W, Wv);
  gemm_bt8<<<dim3(FAN_OUT / BN, B_DIM / BM), 512, 131072, stream>>>(Ae, Wv, out, B_DIM, FAN_OUT);
}